// Round 13
// baseline (348.244 us; speedup 1.0000x reference)
//
#include <hip/hip_runtime.h>
#include <hip/hip_bf16.h>

typedef __attribute__((ext_vector_type(8))) short bf16x8;
typedef __attribute__((ext_vector_type(4))) float f32x4;

#define WIN 256       // edges per block window
#define THR 512       // threads per block (8 waves)

__device__ __forceinline__ unsigned short f2bf(float f) {
    unsigned u = __float_as_uint(f);
    return (unsigned short)((u + 0x7fffu + ((u >> 16) & 1u)) >> 16);
}

__device__ __forceinline__ bf16x8 pack8(float4 x, float4 y) {
    bf16x8 r;
    r[0] = (short)f2bf(x.x); r[1] = (short)f2bf(x.y);
    r[2] = (short)f2bf(x.z); r[3] = (short)f2bf(x.w);
    r[4] = (short)f2bf(y.x); r[5] = (short)f2bf(y.y);
    r[6] = (short)f2bf(y.z); r[7] = (short)f2bf(y.w);
    return r;
}

__device__ __forceinline__ float ftanh(float x) {
    float e = __expf(2.f * x);
    return 1.f - 2.f / (e + 1.f);
}

// ---- pass 1 (tiny): pack the 11 matrices into MFMA A-fragment layout in ws ----
// frag fi in [0,8): elem [fi][lane][j] = bf16(M[(fi>>1)*16 + (lane&15)][ (fi&1)*32 + (lane>>4)*8 + j ])
__global__ void k_pack(const float* __restrict__ layer1, const float* __restrict__ lin_w,
                       __hip_bfloat16* __restrict__ wpack, __hip_bfloat16* __restrict__ lpack) {
    const int m = blockIdx.x;                 // 0..10 (10 = lin_w)
    const float* src = (m < 10) ? (layer1 + m * 4096) : lin_w;
    __hip_bfloat16* dst = (m < 10) ? (wpack + m * 4096) : lpack;
    for (int idx = threadIdx.x; idx < 512; idx += 256) {
        const int fi = idx >> 6, l = idx & 63;
        const int nt = fi >> 1, kk = fi & 1;
        const float* sp = src + (nt * 16 + (l & 15)) * 64 + kk * 32 + (l >> 4) * 8;
        float4 x = *(const float4*)sp;
        float4 y = *(const float4*)(sp + 4);
        *(bf16x8*)(dst + idx * 8) = pack8(x, y);
    }
}

// ---- pass 2: block-local binning + MFMA (no weight redundancy, no masking) ----
// Probe (R12) showed the masked-11x design is VALU-bound (VALUBusy 51%,
// ~640 cndmask / supertile). Here: 256-edge window per block, ballot-rank
// sort into 10 bins (LDS indices only, ~2KB), tiles of 16 same-type edges
// padded with duplicate indices (identical values -> deterministic).
// W frags stream from L2-resident global wpack; lin frags live in registers.
// Fragment layout (verified R1-R5): A row=lane&15, k=(lane>>4)*8+j;
// B col=lane&15 (edge), same k; D col=lane&15, row=(lane>>4)*4+r.
__global__ __launch_bounds__(THR, 4) void k_main(
    const int* __restrict__ ij, const float* __restrict__ desc,
    const __hip_bfloat16* __restrict__ wpack, const __hip_bfloat16* __restrict__ lpack,
    const float* __restrict__ lin_b, float* __restrict__ out, int E) {

    __shared__ int bcnt[10];
    __shared__ int bbase[10];
    __shared__ int ttile[32];          // tile -> type
    __shared__ int otile[32];          // tile -> offset in bidx
    __shared__ int bidx[WIN + 160];    // padded bins
    __shared__ int ntile_s;
    __shared__ float biass[64];

    const int tid = threadIdx.x;
    if (tid < 10) bcnt[tid] = 0;
    if (tid >= 64 && tid < 128) biass[tid - 64] = lin_b[tid - 64];
    __syncthreads();

    // phase 1: rank within bin (threads 0..WIN-1 = waves 0..3, one edge each)
    const int e0 = blockIdx.x * WIN;
    int myrank = -1, myty = 0, mye = 0;
    if (tid < WIN && e0 + tid < E) {
        mye = e0 + tid;
        myty = ij[mye];
        const int lane = tid & 63;
        const unsigned long long ltm = (1ull << lane) - 1ull;
        #pragma unroll
        for (int t = 0; t < 10; ++t) {
            const unsigned long long m = __ballot(myty == t);
            if (myty == t) {
                const int c = (int)__popcll(m);
                const int leader = __ffsll((long long)m) - 1;
                int base = 0;
                if (lane == leader) base = atomicAdd(&bcnt[t], c);
                base = __shfl(base, leader);
                myrank = base + (int)__popcll(m & ltm);
            }
        }
    }
    __syncthreads();
    // phase 2: bin bases (16-padded) + tile list
    if (tid == 0) {
        int off = 0, nt = 0;
        for (int t = 0; t < 10; ++t) {
            bbase[t] = off;
            const int c = bcnt[t];
            const int til = (c + 15) >> 4;
            for (int k = 0; k < til; ++k) { ttile[nt] = t; otile[nt] = off + k * 16; ++nt; }
            off += til << 4;
        }
        ntile_s = nt;
    }
    __syncthreads();
    // phase 3: scatter indices
    if (myrank >= 0) bidx[bbase[myty] + myrank] = mye;
    __syncthreads();
    // phase 4: pad bins to multiple of 16 with their first entry
    if (tid < 160) {
        const int t = tid >> 4;
        const int c = bcnt[t];
        const int s = c + (tid & 15);
        const int pad = ((c + 15) >> 4) << 4;
        if (c > 0 && s < pad) bidx[bbase[t] + s] = bidx[bbase[t]];
    }

    const int lane = tid & 63;
    const int wid = tid >> 6;
    const int col = lane & 15;
    const int g = lane >> 4;
    const int kb = g * 8;

    // lin fragments resident in registers
    bf16x8 al[4][2];
    #pragma unroll
    for (int fi = 0; fi < 8; ++fi)
        al[fi >> 1][fi & 1] = *(const bf16x8*)(lpack + fi * 512 + lane * 8);

    __syncthreads();
    const int NT = ntile_s;

    for (int tl = wid; tl < NT; tl += 8) {
        const int ty = ttile[tl];
        const int eix = bidx[otile[tl] + col];
        const float* dp = desc + (size_t)eix * 64 + kb;
        const float4 x0 = *(const float4*)dp,        y0 = *(const float4*)(dp + 4);
        const float4 x1 = *(const float4*)(dp + 32), y1 = *(const float4*)(dp + 36);
        const bf16x8 b0 = pack8(x0, y0);
        const bf16x8 b1 = pack8(x1, y1);
        const __hip_bfloat16* wp = wpack + ty * 4096;
        float* op = out + (size_t)eix * 64 + g * 4;

        #pragma unroll 1
        for (int nt4 = 0; nt4 < 4; ++nt4) {
            const bf16x8 f0 = *(const bf16x8*)(wp + (nt4 * 2 + 0) * 512 + lane * 8);
            const bf16x8 f1 = *(const bf16x8*)(wp + (nt4 * 2 + 1) * 512 + lane * 8);
            f32x4 zW = {0.f, 0.f, 0.f, 0.f}, zL = {0.f, 0.f, 0.f, 0.f};
            zW = __builtin_amdgcn_mfma_f32_16x16x32_bf16(f0, b0, zW, 0, 0, 0);
            zW = __builtin_amdgcn_mfma_f32_16x16x32_bf16(f1, b1, zW, 0, 0, 0);
            zL = __builtin_amdgcn_mfma_f32_16x16x32_bf16(al[nt4][0], b0, zL, 0, 0, 0);
            zL = __builtin_amdgcn_mfma_f32_16x16x32_bf16(al[nt4][1], b1, zL, 0, 0, 0);
            const float4 bias = *(const float4*)(biass + nt4 * 16 + g * 4);
            f32x4 r;
            r[0] = ftanh(zW[0]) + zL[0] + bias.x;
            r[1] = ftanh(zW[1]) + zL[1] + bias.y;
            r[2] = ftanh(zW[2]) + zL[2] + bias.z;
            r[3] = ftanh(zW[3]) + zL[3] + bias.w;
            *(f32x4*)(op + nt4 * 16) = r;
        }
    }
}

// ---------------- fallback (ws too small): wave-per-edge fp32 ----------------
__global__ void k_naive(const int* __restrict__ ij, const float* __restrict__ desc,
                        const float* __restrict__ layer1, const float* __restrict__ lin_w,
                        const float* __restrict__ lin_b, float* __restrict__ out, int E) {
    const int wid = (blockIdx.x * blockDim.x + threadIdx.x) >> 6;
    const int lane = threadIdx.x & 63;
    const int nw = (gridDim.x * blockDim.x) >> 6;
    for (int e = wid; e < E; e += nw) {
        const int t = ij[e];
        const float d = desc[(size_t)e * 64 + lane];
        const float* Wr = layer1 + t * 4096 + lane * 64;
        const float* Lr = lin_w + lane * 64;
        float a1 = 0.f, a2 = 0.f;
        #pragma unroll
        for (int i = 0; i < 64; i += 4) {
            float4 w4 = *(const float4*)(Wr + i);
            float4 l4 = *(const float4*)(Lr + i);
            const float d0 = __shfl(d, i), d1 = __shfl(d, i + 1);
            const float d2 = __shfl(d, i + 2), d3 = __shfl(d, i + 3);
            a1 = fmaf(w4.x, d0, fmaf(w4.y, d1, fmaf(w4.z, d2, fmaf(w4.w, d3, a1))));
            a2 = fmaf(l4.x, d0, fmaf(l4.y, d1, fmaf(l4.z, d2, fmaf(l4.w, d3, a2))));
        }
        out[(size_t)e * 64 + lane] = tanhf(a1) + a2 + lin_b[lane];
    }
}

extern "C" void kernel_launch(void* const* d_in, const int* in_sizes, int n_in,
                              void* d_out, int out_size, void* d_ws, size_t ws_size,
                              hipStream_t stream) {
    const int* ij = (const int*)d_in[0];
    const float* desc = (const float*)d_in[1];
    const float* layer1 = (const float*)d_in[2];
    const float* lin_w = (const float*)d_in[3];
    const float* lin_b = (const float*)d_in[4];
    float* out = (float*)d_out;
    const int E = in_sizes[0];

    const size_t need = (size_t)11 * 4096 * sizeof(__hip_bfloat16) + 64;
    if (ws_size < need) {
        k_naive<<<2048, 256, 0, stream>>>(ij, desc, layer1, lin_w, lin_b, out, E);
        return;
    }
    __hip_bfloat16* wpack = (__hip_bfloat16*)d_ws;   // 10*4096 bf16
    __hip_bfloat16* lpack = wpack + 10 * 4096;       // 4096 bf16

    k_pack<<<11, 256, 0, stream>>>(layer1, lin_w, wpack, lpack);
    const int nblk = (E + WIN - 1) / WIN;
    k_main<<<nblk, THR, 0, stream>>>(ij, desc, wpack, lpack, lin_b, out, E);
}

// Round 14
// 302.160 us; speedup vs baseline: 1.1525x; 1.1525x over previous
//
#include <hip/hip_runtime.h>
#include <hip/hip_bf16.h>

typedef __attribute__((ext_vector_type(8))) short bf16x8;
typedef __attribute__((ext_vector_type(4))) float f32x4;

#define WIN 512        // edges per block window
#define THR 1024       // threads per block (16 waves); 1 block/CU, 4 waves/SIMD

__device__ __forceinline__ unsigned short f2bf(float f) {
    unsigned u = __float_as_uint(f);
    return (unsigned short)((u + 0x7fffu + ((u >> 16) & 1u)) >> 16);
}

__device__ __forceinline__ bf16x8 pack8(float4 x, float4 y) {
    bf16x8 r;
    r[0] = (short)f2bf(x.x); r[1] = (short)f2bf(x.y);
    r[2] = (short)f2bf(x.z); r[3] = (short)f2bf(x.w);
    r[4] = (short)f2bf(y.x); r[5] = (short)f2bf(y.y);
    r[6] = (short)f2bf(y.z); r[7] = (short)f2bf(y.w);
    return r;
}

__device__ __forceinline__ float ftanh(float x) {
    float e = __expf(2.f * x);
    return 1.f - 2.f / (e + 1.f);
}

// Single fused kernel = R12's LDS-resident weights (19us steady, 0 bank
// conflicts) + R13's block-local binning (kills the masked-11x VALU tax that
// R12's probe measured at VALUBusy 51%). R13's own failure mode — per-tile
// GLOBAL fragment re-reads (L2 same-line contention, 352us) — is avoided:
// fragments only ever read from LDS (W) or registers (lin).
// Layout (verified R1-R12): A row=lane&15, k=(lane>>4)*8+j; B col=lane&15
// (edge), same k; D col=lane&15 (edge), row=(lane>>4)*4+r -> f32x4 store/nt.
__global__ __launch_bounds__(THR, 4) void k_fused(
    const int* __restrict__ ij, const float* __restrict__ desc,
    const float* __restrict__ layer1, const float* __restrict__ lin_w,
    const float* __restrict__ lin_b, float* __restrict__ out, int E) {

    __shared__ __align__(16) short wsm[11 * 512 * 8];   // 88 KiB; m=10 is lin_w
    __shared__ int bcnt[16], bbase[16], tstart[16], tilc[16];
    __shared__ int ttile[48], otile[48];
    __shared__ int ntile_s;
    __shared__ int bidx[WIN + 160];
    __shared__ float biass[64];

    const int tid = threadIdx.x;

    // ---- stage all 11 matrices into LDS (A-fragment layout), zero counters ----
    for (int idx = tid; idx < 11 * 512; idx += THR) {
        const int m = idx >> 9;
        const int fl = idx & 511;
        const int fi = fl >> 6, l = fl & 63;
        const int nt = fi >> 1, kk = fi & 1;
        const float* src = (m < 10) ? (layer1 + m * 4096) : lin_w;
        const float* sp = src + (nt * 16 + (l & 15)) * 64 + kk * 32 + (l >> 4) * 8;
        float4 x = *(const float4*)sp;
        float4 y = *(const float4*)(sp + 4);
        *(bf16x8*)(&wsm[idx * 8]) = pack8(x, y);
    }
    if (tid < 16) bcnt[tid] = 0;
    if (tid >= 64 && tid < 128) biass[tid - 64] = lin_b[tid - 64];
    __syncthreads();

    // ---- bin the block's 512-edge window by type (ballot ranks, 8 waves) ----
    const int e0 = blockIdx.x * WIN;
    int myrank = -1, myty = 0, mye = 0;
    if (tid < WIN && e0 + tid < E) {
        mye = e0 + tid;
        myty = ij[mye];
        const int lane = tid & 63;
        const unsigned long long ltm = (1ull << lane) - 1ull;
        #pragma unroll
        for (int t = 0; t < 10; ++t) {
            const unsigned long long m = __ballot(myty == t);
            if (myty == t) {
                const int c = (int)__popcll(m);
                const int leader = __ffsll((long long)m) - 1;
                int base = 0;
                if (lane == leader) base = atomicAdd(&bcnt[t], c);
                base = __shfl(base, leader);
                myrank = base + (int)__popcll(m & ltm);
            }
        }
    }
    __syncthreads();
    // ---- 10-entry scan (bin bases, tile starts) ----
    if (tid == 0) {
        int off = 0, nt = 0;
        for (int t = 0; t < 10; ++t) {
            bbase[t] = off;
            const int tc = (bcnt[t] + 15) >> 4;
            tstart[t] = nt; tilc[t] = tc;
            nt += tc; off += tc << 4;
        }
        ntile_s = nt;
    }
    __syncthreads();
    // ---- scatter indices + build tile list (parallel) ----
    if (myrank >= 0) bidx[bbase[myty] + myrank] = mye;
    if (tid < 320) {
        const int t = tid >> 5, k = tid & 31;
        if (k < tilc[t]) { ttile[tstart[t] + k] = t; otile[tstart[t] + k] = bbase[t] + k * 16; }
    }
    __syncthreads();
    // ---- pad bins to tile multiple with duplicated first entry ----
    if (tid < 160) {
        const int t = tid >> 4;
        const int c = bcnt[t];
        const int s = c + (tid & 15);
        if (c > 0 && s < (tilc[t] << 4)) bidx[bbase[t] + s] = bidx[bbase[t]];
    }

    const int lane = tid & 63;
    const int wid = tid >> 6;
    const int col = lane & 15;
    const int g = lane >> 4;
    const int kb = g * 8;

    // lin fragments resident in registers (read from staged LDS, m=10)
    bf16x8 al[4][2];
    __syncthreads();
    #pragma unroll
    for (int fi = 0; fi < 8; ++fi)
        al[fi >> 1][fi & 1] = *(const bf16x8*)(&wsm[((80 + fi) * 64 + lane) * 8]);
    const int NT = ntile_s;

    // ---- tile loop: 16 waves, no masking, frags from LDS only ----
    for (int tl = wid; tl < NT; tl += 16) {
        const int ty = ttile[tl];
        const int eix = bidx[otile[tl] + col];
        const float* dp = desc + (size_t)eix * 64 + kb;
        const float4 x0 = *(const float4*)dp,        y0 = *(const float4*)(dp + 4);
        const float4 x1 = *(const float4*)(dp + 32), y1 = *(const float4*)(dp + 36);
        const bf16x8 b0 = pack8(x0, y0);
        const bf16x8 b1 = pack8(x1, y1);
        float* op = out + (size_t)eix * 64 + g * 4;

        #pragma unroll 1
        for (int nt4 = 0; nt4 < 4; ++nt4) {
            const bf16x8 f0 = *(const bf16x8*)(&wsm[((ty * 8 + nt4 * 2 + 0) * 64 + lane) * 8]);
            const bf16x8 f1 = *(const bf16x8*)(&wsm[((ty * 8 + nt4 * 2 + 1) * 64 + lane) * 8]);
            f32x4 zW = {0.f, 0.f, 0.f, 0.f}, zL = {0.f, 0.f, 0.f, 0.f};
            zW = __builtin_amdgcn_mfma_f32_16x16x32_bf16(f0, b0, zW, 0, 0, 0);
            zW = __builtin_amdgcn_mfma_f32_16x16x32_bf16(f1, b1, zW, 0, 0, 0);
            zL = __builtin_amdgcn_mfma_f32_16x16x32_bf16(al[nt4][0], b0, zL, 0, 0, 0);
            zL = __builtin_amdgcn_mfma_f32_16x16x32_bf16(al[nt4][1], b1, zL, 0, 0, 0);
            const float4 bias = *(const float4*)(biass + nt4 * 16 + g * 4);
            f32x4 r;
            r[0] = ftanh(zW[0]) + zL[0] + bias.x;
            r[1] = ftanh(zW[1]) + zL[1] + bias.y;
            r[2] = ftanh(zW[2]) + zL[2] + bias.z;
            r[3] = ftanh(zW[3]) + zL[3] + bias.w;
            *(f32x4*)(op + nt4 * 16) = r;
        }
    }
}

extern "C" void kernel_launch(void* const* d_in, const int* in_sizes, int n_in,
                              void* d_out, int out_size, void* d_ws, size_t ws_size,
                              hipStream_t stream) {
    const int* ij = (const int*)d_in[0];
    const float* desc = (const float*)d_in[1];
    const float* layer1 = (const float*)d_in[2];
    const float* lin_w = (const float*)d_in[3];
    const float* lin_b = (const float*)d_in[4];
    float* out = (float*)d_out;
    const int E = in_sizes[0];

    const int nblk = (E + WIN - 1) / WIN;
    k_fused<<<nblk, THR, 0, stream>>>(ij, desc, layer1, lin_w, lin_b, out, E);
}

// Round 15
// 26.338 us; speedup vs baseline: 13.2222x; 11.4725x over previous
//
#include <hip/hip_runtime.h>
#include <hip/hip_bf16.h>

typedef __attribute__((ext_vector_type(8))) short bf16x8;
typedef __attribute__((ext_vector_type(4))) float f32x4;

#define NBLK 256   // blocks; 1024 threads each; 1 block/CU (88 KB LDS), 4 waves/SIMD

__device__ __forceinline__ unsigned short f2bf(float f) {
    unsigned u = __float_as_uint(f);
    return (unsigned short)((u + 0x7fffu + ((u >> 16) & 1u)) >> 16);
}

__device__ __forceinline__ bf16x8 pack8(float4 x, float4 y) {
    bf16x8 r;
    r[0] = (short)f2bf(x.x); r[1] = (short)f2bf(x.y);
    r[2] = (short)f2bf(x.z); r[3] = (short)f2bf(x.w);
    r[4] = (short)f2bf(y.x); r[5] = (short)f2bf(y.y);
    r[6] = (short)f2bf(y.z); r[7] = (short)f2bf(y.w);
    return r;
}

__device__ __forceinline__ float ftanh(float x) {
    float e = __expf(2.f * x);
    return 1.f - 2.f / (e + 1.f);
}

// Masked-fused kernel (R11 base = 30.0us; R12 probe: steady 19us, VALU-bound
// at 51% from per-(nt,m) re-masking). This round: m-OUTER loop -> mask built
// ONCE per type (1 cmp + 16 cndmask) and reused by the unrolled nt x4 MFMA
// block (~10 cndmask/edge vs ~27 before); types absent from the tile skipped
// via __any (16 random edges -> ~8.1 of 10 types present). 16 edges/wave-pass
// keeps live set ~85 VGPR (no spill; rounds 6-8 lesson).
// NOTE (R13/R14): block-local binning inside the consumer kernel is ~10x
// SLOWER despite removing masking — do not revisit that branch.
// Fragment layout (verified R1-R5): A row=lane&15, k=(lane>>4)*8+j;
// B col=lane&15 (edge), same k; D col=lane&15 (edge), row=(lane>>4)*4+r.
__global__ __launch_bounds__(1024, 4) void k_fused(
    const int* __restrict__ ij, const float* __restrict__ desc,
    const float* __restrict__ layer1, const float* __restrict__ lin_w,
    const float* __restrict__ lin_b, float* __restrict__ out, int E) {

    __shared__ __align__(16) short wsm[11 * 512 * 8];   // 88 KiB; m=10 is lin_w

    for (int idx = threadIdx.x; idx < 11 * 512; idx += 1024) {
        const int m = idx >> 9;
        const int fl = idx & 511;
        const int fi = fl >> 6, l = fl & 63;
        const int nt = fi >> 1, kk = fi & 1;
        const float* src = (m < 10) ? (layer1 + m * 4096) : lin_w;
        const float* sp = src + (nt * 16 + (l & 15)) * 64 + kk * 32 + (l >> 4) * 8;
        float4 x = *(const float4*)sp;
        float4 y = *(const float4*)(sp + 4);
        *(bf16x8*)(&wsm[idx * 8]) = pack8(x, y);
    }

    const int lane = threadIdx.x & 63;
    const int col = lane & 15;
    const int g = lane >> 4;
    const int kb = g * 8;
    const bf16x8 zero8 = {0, 0, 0, 0, 0, 0, 0, 0};

    __syncthreads();

    const int gw = blockIdx.x * 16 + (threadIdx.x >> 6);
    const int ntl = (E + 15) >> 4;       // 16-edge tiles; E=131072 -> 8192 = 2 per wave
    for (int s = gw; s < ntl; s += NBLK * 16) {
        const int e = s * 16 + col;
        const int ec = min(e, E - 1);
        const int ty = ij[ec];
        const float* dp = desc + (size_t)ec * 64 + kb;
        const float4 x0 = *(const float4*)dp,        y0 = *(const float4*)(dp + 4);
        const float4 x1 = *(const float4*)(dp + 32), y1 = *(const float4*)(dp + 36);
        const bf16x8 b0 = pack8(x0, y0);
        const bf16x8 b1 = pack8(x1, y1);

        // lin path (m=10 frags, unmasked) + zero W accumulators
        f32x4 zL[4], zW[4];
        #pragma unroll
        for (int nt = 0; nt < 4; ++nt) {
            const bf16x8 f0 = *(const bf16x8*)(&wsm[((80 + nt * 2 + 0) * 64 + lane) * 8]);
            const bf16x8 f1 = *(const bf16x8*)(&wsm[((80 + nt * 2 + 1) * 64 + lane) * 8]);
            f32x4 z = {0.f, 0.f, 0.f, 0.f};
            z = __builtin_amdgcn_mfma_f32_16x16x32_bf16(f0, b0, z, 0, 0, 0);
            zL[nt] = __builtin_amdgcn_mfma_f32_16x16x32_bf16(f1, b1, z, 0, 0, 0);
            zW[nt] = (f32x4){0.f, 0.f, 0.f, 0.f};
        }

        // W path: m OUTER, mask built once per present type, nt unrolled inside
        #pragma unroll 1
        for (int m = 0; m < 10; ++m) {
            if (!__any(ty == m)) continue;          // type absent from tile
            const bf16x8 m0 = (ty == m) ? b0 : zero8;
            const bf16x8 m1 = (ty == m) ? b1 : zero8;
            #pragma unroll
            for (int nt = 0; nt < 4; ++nt) {
                const bf16x8 f0 = *(const bf16x8*)(&wsm[((m * 8 + nt * 2 + 0) * 64 + lane) * 8]);
                const bf16x8 f1 = *(const bf16x8*)(&wsm[((m * 8 + nt * 2 + 1) * 64 + lane) * 8]);
                zW[nt] = __builtin_amdgcn_mfma_f32_16x16x32_bf16(f0, m0, zW[nt], 0, 0, 0);
                zW[nt] = __builtin_amdgcn_mfma_f32_16x16x32_bf16(f1, m1, zW[nt], 0, 0, 0);
            }
        }

        if (e < E) {
            float* op = out + (size_t)e * 64 + g * 4;
            #pragma unroll
            for (int nt = 0; nt < 4; ++nt) {
                const float4 bias = *(const float4*)(lin_b + nt * 16 + g * 4);
                f32x4 r;
                r[0] = ftanh(zW[nt][0]) + zL[nt][0] + bias.x;
                r[1] = ftanh(zW[nt][1]) + zL[nt][1] + bias.y;
                r[2] = ftanh(zW[nt][2]) + zL[nt][2] + bias.z;
                r[3] = ftanh(zW[nt][3]) + zL[nt][3] + bias.w;
                *(f32x4*)(op + nt * 16) = r;
            }
        }
    }
}

extern "C" void kernel_launch(void* const* d_in, const int* in_sizes, int n_in,
                              void* d_out, int out_size, void* d_ws, size_t ws_size,
                              hipStream_t stream) {
    const int* ij = (const int*)d_in[0];
    const float* desc = (const float*)d_in[1];
    const float* layer1 = (const float*)d_in[2];
    const float* lin_w = (const float*)d_in[3];
    const float* lin_b = (const float*)d_in[4];
    float* out = (float*)d_out;
    const int E = in_sizes[0];

    k_fused<<<NBLK, 1024, 0, stream>>>(ij, desc, layer1, lin_w, lin_b, out, E);
}

// Round 16
// 24.147 us; speedup vs baseline: 14.4220x; 1.0907x over previous
//
#include <hip/hip_runtime.h>
#include <hip/hip_bf16.h>

typedef __attribute__((ext_vector_type(8))) short bf16x8;
typedef __attribute__((ext_vector_type(4))) float f32x4;

#define NBLK 256   // blocks; 512 threads (8 waves); 1 block/CU (88 KB LDS), 2 waves/SIMD

__device__ __forceinline__ unsigned short f2bf(float f) {
    unsigned u = __float_as_uint(f);
    return (unsigned short)((u + 0x7fffu + ((u >> 16) & 1u)) >> 16);
}

__device__ __forceinline__ bf16x8 pack8(float4 x, float4 y) {
    bf16x8 r;
    r[0] = (short)f2bf(x.x); r[1] = (short)f2bf(x.y);
    r[2] = (short)f2bf(x.z); r[3] = (short)f2bf(x.w);
    r[4] = (short)f2bf(y.x); r[5] = (short)f2bf(y.y);
    r[6] = (short)f2bf(y.z); r[7] = (short)f2bf(y.w);
    return r;
}

__device__ __forceinline__ float ftanh(float x) {
    float e = __expf(2.f * x);
    return 1.f - 2.f / (e + 1.f);
}

// Masked-fused kernel + IN-WAVE BALLOT SORT. Each wave owns a 64-edge window:
// stable ballot-rank by type (bijective), ds_permute pushes (e,ty) into sorted
// lane order -> the wave's 4 tiles of 16 are sorted runs. E[distinct types per
// tile] drops 8.1 -> ~3.1 (boundaries in a 16-slice of sorted 64 = 9*15/63),
// cutting m-iterations / frag ds_reads / MFMA / cndmask ~2.5x. Sort is pure
// wave-register ops (no LDS binning, no syncs — avoids the R13/R14 structure
// that regressed 10x). m-loop runs [ty_lo, ty_hi] of the tile + __any skip.
// 2048 waves (one window each), 2 waves/SIMD -> VGPR cap 256: lin frags
// hoisted to registers. Layout (verified R1-R5): A row=lane&15,
// k=(lane>>4)*8+j; B col=lane&15 (edge); D col=lane&15, row=(lane>>4)*4+r.
__global__ __launch_bounds__(512, 2) void k_fused(
    const int* __restrict__ ij, const float* __restrict__ desc,
    const float* __restrict__ layer1, const float* __restrict__ lin_w,
    const float* __restrict__ lin_b, float* __restrict__ out, int E) {

    __shared__ __align__(16) short wsm[11 * 512 * 8];   // 88 KiB; m=10 is lin_w

    for (int idx = threadIdx.x; idx < 11 * 512; idx += 512) {
        const int m = idx >> 9;
        const int fl = idx & 511;
        const int fi = fl >> 6, l = fl & 63;
        const int nt = fi >> 1, kk = fi & 1;
        const float* src = (m < 10) ? (layer1 + m * 4096) : lin_w;
        const float* sp = src + (nt * 16 + (l & 15)) * 64 + kk * 32 + (l >> 4) * 8;
        float4 x = *(const float4*)sp;
        float4 y = *(const float4*)(sp + 4);
        *(bf16x8*)(&wsm[idx * 8]) = pack8(x, y);
    }

    const int lane = threadIdx.x & 63;
    const int col = lane & 15;
    const int g = lane >> 4;
    const int kb = g * 8;
    const bf16x8 zero8 = {0, 0, 0, 0, 0, 0, 0, 0};

    __syncthreads();

    // lin fragments resident in registers (m=10 staged frags)
    bf16x8 al[4][2];
    #pragma unroll
    for (int fi = 0; fi < 8; ++fi)
        al[fi >> 1][fi & 1] = *(const bf16x8*)(&wsm[((80 + fi) * 64 + lane) * 8]);

    const int gw = blockIdx.x * 8 + (threadIdx.x >> 6);
    const int base = gw * 64;
    if (base >= E) return;

    // ---- in-wave sort of the 64-edge window by type (stable ballot rank) ----
    const int e_own = min(base + lane, E - 1);
    const int ty_own = ij[e_own];
    int rank = 0, below = 0;
    #pragma unroll
    for (int t = 0; t < 10; ++t) {
        const unsigned long long m = __ballot(ty_own == t);
        if (ty_own == t) rank = below + (int)__popcll(m & ((1ull << lane) - 1ull));
        below += (int)__popcll(m);
    }
    const int e_sorted = __builtin_amdgcn_ds_permute(rank << 2, e_own);
    const int ty_sorted = __builtin_amdgcn_ds_permute(rank << 2, ty_own);

    // ---- 4 sorted 16-edge tiles ----
    #pragma unroll 1
    for (int tp = 0; tp < 4; ++tp) {
        const int pbase = tp * 16;
        const int e_t = __shfl(e_sorted, pbase + col);
        const int ty_t = __shfl(ty_sorted, pbase + col);
        const int ty_lo = __shfl(ty_sorted, pbase);
        const int ty_hi = __shfl(ty_sorted, pbase + 15);

        const float* dp = desc + (size_t)e_t * 64 + kb;
        const float4 x0 = *(const float4*)dp,        y0 = *(const float4*)(dp + 4);
        const float4 x1 = *(const float4*)(dp + 32), y1 = *(const float4*)(dp + 36);
        const bf16x8 b0 = pack8(x0, y0);
        const bf16x8 b1 = pack8(x1, y1);

        // lin path + zero W accumulators
        f32x4 zL[4], zW[4];
        #pragma unroll
        for (int nt = 0; nt < 4; ++nt) {
            f32x4 z = {0.f, 0.f, 0.f, 0.f};
            z = __builtin_amdgcn_mfma_f32_16x16x32_bf16(al[nt][0], b0, z, 0, 0, 0);
            zL[nt] = __builtin_amdgcn_mfma_f32_16x16x32_bf16(al[nt][1], b1, z, 0, 0, 0);
            zW[nt] = (f32x4){0.f, 0.f, 0.f, 0.f};
        }

        // W path over the tile's (sorted, contiguous) type range
        #pragma unroll 1
        for (int m = ty_lo; m <= ty_hi; ++m) {
            if (!__any(ty_t == m)) continue;
            const bf16x8 m0 = (ty_t == m) ? b0 : zero8;
            const bf16x8 m1 = (ty_t == m) ? b1 : zero8;
            #pragma unroll
            for (int nt = 0; nt < 4; ++nt) {
                const bf16x8 f0 = *(const bf16x8*)(&wsm[((m * 8 + nt * 2 + 0) * 64 + lane) * 8]);
                const bf16x8 f1 = *(const bf16x8*)(&wsm[((m * 8 + nt * 2 + 1) * 64 + lane) * 8]);
                zW[nt] = __builtin_amdgcn_mfma_f32_16x16x32_bf16(f0, m0, zW[nt], 0, 0, 0);
                zW[nt] = __builtin_amdgcn_mfma_f32_16x16x32_bf16(f1, m1, zW[nt], 0, 0, 0);
            }
        }

        float* op = out + (size_t)e_t * 64 + g * 4;
        #pragma unroll
        for (int nt = 0; nt < 4; ++nt) {
            const float4 bias = *(const float4*)(lin_b + nt * 16 + g * 4);
            f32x4 r;
            r[0] = ftanh(zW[nt][0]) + zL[nt][0] + bias.x;
            r[1] = ftanh(zW[nt][1]) + zL[nt][1] + bias.y;
            r[2] = ftanh(zW[nt][2]) + zL[nt][2] + bias.z;
            r[3] = ftanh(zW[nt][3]) + zL[nt][3] + bias.w;
            *(f32x4*)(op + nt * 16) = r;
        }
    }
}

extern "C" void kernel_launch(void* const* d_in, const int* in_sizes, int n_in,
                              void* d_out, int out_size, void* d_ws, size_t ws_size,
                              hipStream_t stream) {
    const int* ij = (const int*)d_in[0];
    const float* desc = (const float*)d_in[1];
    const float* layer1 = (const float*)d_in[2];
    const float* lin_w = (const float*)d_in[3];
    const float* lin_b = (const float*)d_in[4];
    float* out = (float*)d_out;
    const int E = in_sizes[0];

    k_fused<<<NBLK, 512, 0, stream>>>(ij, desc, layer1, lin_w, lin_b, out, E);
}